// Round 6
// baseline (313.531 us; speedup 1.0000x reference)
//
#include <hip/hip_runtime.h>
#include <stdint.h>

// ---------------------------------------------------------------------------
// MultiDilatelocalAttention (B=4, H=W=128, C=256, heads=8, K=3, dil={2,3})
//   1) qkv = x @ Wqkv^T            (bf16 MFMA GEMM, M=65536 N=768 K=256)
//   2) dilated 3x3 local attention (lane-pair split, fp32/f32x2)
//   3) out = xo @ Wproj^T + bproj  (bf16 MFMA GEMM, fp32 out)
// GEMM: 128x128 tile, BK=64, KT=4 fully unrolled, double-buffered LDS with
// counted-vmcnt pipeline (T3/T4), XCD-chunked N-major block swizzle (T1),
// T2 XOR-swizzled LDS tiles, LDS-staged coalesced epilogue.
// R6: attn rewritten — was latency-bound (VALUBusy 34%, HBM 22%, VGPR 44 =>
// serialized load chains). Now: 16 ch/thread (lane-pair halves, shfl_xor
// combine), per-i-row batched loads (6 independent uint4 in flight), OOB taps
// load zero vectors (exact zero-pad semantics, no divergent compute), f32x2
// math for v_pk_fma_f32, scale folded into q.
// ---------------------------------------------------------------------------

typedef __attribute__((ext_vector_type(8))) short bf16x8;
typedef __attribute__((ext_vector_type(4))) float f32x4;
typedef __attribute__((ext_vector_type(2))) float f32x2;

__device__ __forceinline__ f32x2 up2(unsigned u) {
  union { unsigned u; float f; } a, b;
  a.u = u << 16;
  b.u = u & 0xffff0000u;
  return (f32x2){a.f, b.f};
}
__device__ __forceinline__ unsigned short f2bf(float f) {
  union { float f; unsigned u; } x; x.f = f;
  unsigned r = x.u + 0x7fffu + ((x.u >> 16) & 1u);   // RNE
  return (unsigned short)(r >> 16);
}
__device__ __forceinline__ unsigned pk2bf(float a, float b) {
  return (unsigned)f2bf(a) | ((unsigned)f2bf(b) << 16);
}

// ------------------------------- fp32 -> bf16 ------------------------------
__global__ __launch_bounds__(256) void cvt_f32_to_bf16(
    const float* __restrict__ src, unsigned short* __restrict__ dst, int n) {
  int i = (blockIdx.x * 256 + threadIdx.x) * 8;
  if (i + 8 <= n) {
    const float4* s = (const float4*)(src + i);
    float4 a = s[0], b = s[1];
    uint4 o;
    o.x = pk2bf(a.x, a.y); o.y = pk2bf(a.z, a.w);
    o.z = pk2bf(b.x, b.y); o.w = pk2bf(b.z, b.w);
    *(uint4*)(dst + i) = o;
  } else {
    for (; i < n; ++i) dst[i] = f2bf(src[i]);
  }
}

// ------------------------- GEMM: C = A @ B^T (bf16) ------------------------
// Barrier with LDS-op drain (cross-wave ds_write/ds_read ordering) + sched
// fence (rule #18: keep the scheduler from hoisting past the waitcnt).
#define BARX()                                                \
  do {                                                        \
    asm volatile("s_waitcnt lgkmcnt(0)" ::: "memory");        \
    __builtin_amdgcn_s_barrier();                             \
    __builtin_amdgcn_sched_barrier(0);                        \
  } while (0)
#define WAITVM(n)                                             \
  do {                                                        \
    asm volatile("s_waitcnt vmcnt(" #n ")" ::: "memory");     \
    __builtin_amdgcn_sched_barrier(0);                        \
  } while (0)

template <int OUTF32>
__global__ __launch_bounds__(256) void gemm_bt(
    const unsigned short* __restrict__ A, const unsigned short* __restrict__ B,
    void* __restrict__ Cout, const float* __restrict__ bias,
    int N, int NT) {
  // A0 | B0 | A1 | B1, each 128x64 bf16 = 16 KB. Total 64 KB, reused by epilogue.
  __shared__ __align__(16) unsigned short lds[4][8192];

  const int tid  = threadIdx.x;
  const int lane = tid & 63;
  const int wv   = tid >> 6;
  const int wr   = wv >> 1;   // wave row (0..1)
  const int wc   = wv & 1;    // wave col (0..1)

  // XCD-chunked bijective swizzle (gridDim.x % 8 == 0), N-major tile order:
  // consecutive nid share the same A 128-row panel -> L2 reuse within an XCD.
  const int nwg = gridDim.x;
  const int q8  = nwg >> 3;
  const int nid = (blockIdx.x & 7) * q8 + (blockIdx.x >> 3);
  const int n0  = (nid % NT) * 128;
  const int m0  = (nid / NT) * 128;

  // staging: per issue `it`, wave wv writes LDS bytes [it*4096 + wv*1024, +1024)
  // (HW: uniform base + lane*16). LDS elem = it*2048 + wv*512 + l*8
  //   -> row = it*32 + wv*8 + l/8 (row&7 == l>>3), granule = l&7.
  // T2: lane fetches global granule (l&7)^(l>>3) so LDS content is XOR-swizzled.
  const int stg_row = wv * 8 + (lane >> 3);
  const int stg_k   = ((lane & 7) ^ (lane >> 3)) * 8;
  const unsigned short* Ag = A + (size_t)(m0 + stg_row) * 256 + stg_k;
  const unsigned short* Bg = B + (size_t)(n0 + stg_row) * 256 + stg_k;

  f32x4 acc[4][4];
#pragma unroll
  for (int i = 0; i < 4; ++i)
#pragma unroll
    for (int j = 0; j < 4; ++j) acc[i][j] = (f32x4){0.f, 0.f, 0.f, 0.f};

  const int a_r = lane & 15;         // row within 16x16 fragment
  // nominal k-granule for this lane at kk: (kk>>3) + (lane>>4); all fragment
  // rows are ==0 mod 8 + a_r, so row&7 == lane&7 for A and B alike.
  const int rsw = lane & 7;

#define STAGE(buf, kt)                                                         \
  do {                                                                         \
    const unsigned short* Asrc = Ag + (kt) * 64;                               \
    const unsigned short* Bsrc = Bg + (kt) * 64;                               \
    _Pragma("unroll")                                                          \
    for (int it = 0; it < 4; ++it) {                                           \
      __builtin_amdgcn_global_load_lds(                                        \
          (const __attribute__((address_space(1))) void*)(Asrc + (size_t)it * 32 * 256), \
          (__attribute__((address_space(3))) void*)&lds[(buf) * 2][it * 2048 + wv * 512], \
          16, 0, 0);                                                           \
      __builtin_amdgcn_global_load_lds(                                        \
          (const __attribute__((address_space(1))) void*)(Bsrc + (size_t)it * 32 * 256), \
          (__attribute__((address_space(3))) void*)&lds[(buf) * 2 + 1][it * 2048 + wv * 512], \
          16, 0, 0);                                                           \
    }                                                                          \
  } while (0)

#define COMPUTE(buf)                                                           \
  do {                                                                         \
    _Pragma("unroll")                                                          \
    for (int kk = 0; kk < 64; kk += 32) {                                      \
      const int gsw = (((kk >> 3) + (lane >> 4)) ^ rsw) * 8;  /* T2 read swz */\
      bf16x8 af[4], bfr[4];                                                    \
      _Pragma("unroll")                                                        \
      for (int mi = 0; mi < 4; ++mi)                                           \
        af[mi] = *(const bf16x8*)&lds[(buf) * 2][(wr * 64 + mi * 16 + a_r) * 64 + gsw]; \
      _Pragma("unroll")                                                        \
      for (int ni = 0; ni < 4; ++ni)                                           \
        bfr[ni] = *(const bf16x8*)&lds[(buf) * 2 + 1][(wc * 64 + ni * 16 + a_r) * 64 + gsw]; \
      _Pragma("unroll")                                                        \
      for (int mi = 0; mi < 4; ++mi)                                           \
        _Pragma("unroll")                                                      \
        for (int ni = 0; ni < 4; ++ni)                                         \
          acc[mi][ni] = __builtin_amdgcn_mfma_f32_16x16x32_bf16(               \
              af[mi], bfr[ni], acc[mi][ni], 0, 0, 0);                          \
    }                                                                          \
  } while (0)

  // Depth-2 prefetch pipeline, 8 loads/wave per STAGE; vmcnt counted, never 0
  // until the final tile. K-tiles 0..3 rotate through buffers 0,1,0,1.
  STAGE(0, 0);
  STAGE(1, 1);
  WAITVM(8);  BARX();
  COMPUTE(0);            // kt0 in buf0
  BARX();
  STAGE(0, 2);
  WAITVM(8);  BARX();
  COMPUTE(1);            // kt1 in buf1
  BARX();
  STAGE(1, 3);
  WAITVM(8);  BARX();
  COMPUTE(0);            // kt2 in buf0
  BARX();
  WAITVM(0);  BARX();
  COMPUTE(1);            // kt3 in buf1
  BARX();   // LDS about to be reused by epilogue

  // ------------------- LDS-staged coalesced epilogue -------------------
  const int cl = wc * 64 + a_r;              // local col base
  const int rl = wr * 64 + (lane >> 4) * 4;  // local row base
  if (!OUTF32) {
    // 128 rows x (128+8) bf16, stride 272 B (16B-aligned rows, bank spread)
    unsigned short* eb = &lds[0][0];
#pragma unroll
    for (int ni = 0; ni < 4; ++ni)
#pragma unroll
      for (int mi = 0; mi < 4; ++mi)
#pragma unroll
        for (int r = 0; r < 4; ++r)
          eb[(rl + mi * 16 + r) * 136 + cl + ni * 16] = f2bf(acc[mi][ni][r]);
    BARX();   // lgkmcnt(0) drain inside: publishes ds_writes to all waves
    unsigned short* C = (unsigned short*)Cout;
#pragma unroll
    for (int p = 0; p < 8; ++p) {
      const int idx = p * 256 + tid;
      const int row = idx >> 4;
      const int seg = idx & 15;
      uint4 v = *(const uint4*)&eb[row * 136 + seg * 8];
      *(uint4*)&C[(size_t)(m0 + row) * N + n0 + seg * 8] = v;
    }
  } else {
    // f32: two 64-row halves of (128+4)-f32-stride rows (33792 B each)
    float* ef = (float*)&lds[0][0];
    float* C = (float*)Cout;
    float bv[4];
#pragma unroll
    for (int ni = 0; ni < 4; ++ni) bv[ni] = bias[n0 + wc * 64 + ni * 16 + a_r];
#pragma unroll
    for (int half = 0; half < 2; ++half) {
      if (wr == half) {
        const int rb = (lane >> 4) * 4;   // local row within the half
#pragma unroll
        for (int ni = 0; ni < 4; ++ni)
#pragma unroll
          for (int mi = 0; mi < 4; ++mi)
#pragma unroll
            for (int r = 0; r < 4; ++r)
              ef[(rb + mi * 16 + r) * 132 + wc * 64 + ni * 16 + a_r] =
                  acc[mi][ni][r] + bv[ni];
      }
      BARX();   // lgkmcnt(0) drain inside
#pragma unroll
      for (int p = 0; p < 8; ++p) {
        const int idx = p * 256 + tid;
        const int row = idx >> 5;
        const int seg = idx & 31;
        f32x4 v = *(const f32x4*)&ef[row * 132 + seg * 4];
        *(f32x4*)&C[(size_t)(m0 + half * 64 + row) * N + n0 + seg * 4] = v;
      }
      BARX();
    }
  }
#undef STAGE
#undef COMPUTE
}

// --------------------------- dilated local attention -----------------------
// qkv: [pixel][768] bf16, channel o = t*256 + combo*32 + ch (combo=branch*4+head)
// One thread per (pixel, combo, half): 16 channels each; lane pair (l, l^1)
// holds the two halves; full 32-ch dot completed with one shfl_xor per tap.
// OOB taps load a zero vector => score 0 / v 0, matching zero-pad unfold.
__global__ __launch_bounds__(256) void attn_kernel(
    const unsigned short* __restrict__ qkv, unsigned short* __restrict__ xo) {
  // XCD-chunked swizzle: contiguous pixel stripes per XCD for K/V L2 locality
  const int nwg = gridDim.x;
  const int q8  = nwg >> 3;
  const int bid = (blockIdx.x & 7) * q8 + (blockIdx.x >> 3);
  const int gid   = bid * 256 + threadIdx.x;
  const int half  = gid & 1;
  const int combo = (gid >> 1) & 7;
  const int pixel = gid >> 4;
  const int w = pixel & 127;
  const int h = (pixel >> 7) & 127;
  const int b = pixel >> 14;
  const int dil = (combo >> 2) ? 3 : 2;        // DILATIONS = (2, 3)
  const int choff = combo * 32 + half * 16;

  // q (16 ch), scale folded in. Lanes 0-15 read one pixel's q contiguous 512B.
  const unsigned short* qp = qkv + (size_t)pixel * 768 + choff;
  f32x2 q2[8];
  {
    uint4 u0 = *(const uint4*)qp;
    uint4 u1 = *(const uint4*)(qp + 8);
    const f32x2 s2 = {0.17677669529663687f, 0.17677669529663687f};  // 32^-0.5
    q2[0] = up2(u0.x) * s2; q2[1] = up2(u0.y) * s2;
    q2[2] = up2(u0.z) * s2; q2[3] = up2(u0.w) * s2;
    q2[4] = up2(u1.x) * s2; q2[5] = up2(u1.y) * s2;
    q2[6] = up2(u1.z) * s2; q2[7] = up2(u1.w) * s2;
  }

  const uint4 z4 = make_uint4(0u, 0u, 0u, 0u);

  // ---- scores: per i-row, batch all 6 loads, then 3 half-dots ----
  float sc[9];
#pragma unroll
  for (int i = 0; i < 3; ++i) {
    const int hh = h + (i - 1) * dil;
    const bool vrow = (unsigned)hh < 128u;
    uint4 ka[3], kb[3];
#pragma unroll
    for (int j = 0; j < 3; ++j) {
      const int ww = w + (j - 1) * dil;
      const bool ok = vrow && ((unsigned)ww < 128u);
      const unsigned short* kp =
          qkv + (size_t)((((b << 7) | hh) << 7) | ww) * 768 + 256 + choff;
      ka[j] = ok ? *(const uint4*)kp : z4;
      kb[j] = ok ? *(const uint4*)(kp + 8) : z4;
    }
#pragma unroll
    for (int j = 0; j < 3; ++j) {
      f32x2 a = q2[0] * up2(ka[j].x);
      a += q2[1] * up2(ka[j].y);
      a += q2[2] * up2(ka[j].z);
      a += q2[3] * up2(ka[j].w);
      a += q2[4] * up2(kb[j].x);
      a += q2[5] * up2(kb[j].y);
      a += q2[6] * up2(kb[j].z);
      a += q2[7] * up2(kb[j].w);
      sc[i * 3 + j] = a.x + a.y;       // half-dot (scale already in q)
    }
  }
  // complete the 32-ch dot across the lane pair
#pragma unroll
  for (int t = 0; t < 9; ++t) sc[t] += __shfl_xor(sc[t], 1);

  // ---- softmax over 9 (both halves compute identically) ----
  float mx = sc[0];
#pragma unroll
  for (int t = 1; t < 9; ++t) mx = fmaxf(mx, sc[t]);
  float sum = 0.f;
#pragma unroll
  for (int t = 0; t < 9; ++t) { sc[t] = __expf(sc[t] - mx); sum += sc[t]; }
  const float inv = 1.f / sum;

  // ---- weighted V accumulate, same batched structure ----
  f32x2 o2[8];
#pragma unroll
  for (int t = 0; t < 8; ++t) o2[t] = (f32x2){0.f, 0.f};
#pragma unroll
  for (int i = 0; i < 3; ++i) {
    const int hh = h + (i - 1) * dil;
    const bool vrow = (unsigned)hh < 128u;
    uint4 va[3], vb[3];
#pragma unroll
    for (int j = 0; j < 3; ++j) {
      const int ww = w + (j - 1) * dil;
      const bool ok = vrow && ((unsigned)ww < 128u);
      const unsigned short* vp =
          qkv + (size_t)((((b << 7) | hh) << 7) | ww) * 768 + 512 + choff;
      va[j] = ok ? *(const uint4*)vp : z4;
      vb[j] = ok ? *(const uint4*)(vp + 8) : z4;
    }
#pragma unroll
    for (int j = 0; j < 3; ++j) {
      const float wv = sc[i * 3 + j] * inv;
      const f32x2 w2 = {wv, wv};
      o2[0] += w2 * up2(va[j].x);
      o2[1] += w2 * up2(va[j].y);
      o2[2] += w2 * up2(va[j].z);
      o2[3] += w2 * up2(va[j].w);
      o2[4] += w2 * up2(vb[j].x);
      o2[5] += w2 * up2(vb[j].y);
      o2[6] += w2 * up2(vb[j].z);
      o2[7] += w2 * up2(vb[j].w);
    }
  }

  unsigned short* op = xo + (size_t)pixel * 256 + choff;
  uint4 s0, s1;
  s0.x = pk2bf(o2[0].x, o2[0].y); s0.y = pk2bf(o2[1].x, o2[1].y);
  s0.z = pk2bf(o2[2].x, o2[2].y); s0.w = pk2bf(o2[3].x, o2[3].y);
  s1.x = pk2bf(o2[4].x, o2[4].y); s1.y = pk2bf(o2[5].x, o2[5].y);
  s1.z = pk2bf(o2[6].x, o2[6].y); s1.w = pk2bf(o2[7].x, o2[7].y);
  *(uint4*)op = s0;
  *(uint4*)(op + 8) = s1;
}

// ---------------------------------------------------------------------------
extern "C" void kernel_launch(void* const* d_in, const int* in_sizes, int n_in,
                              void* d_out, int out_size, void* d_ws, size_t ws_size,
                              hipStream_t stream) {
  const float* x     = (const float*)d_in[0];
  const float* Wqkv  = (const float*)d_in[1];
  const float* Wproj = (const float*)d_in[2];
  const float* bproj = (const float*)d_in[3];

  const int M = 4 * 128 * 128;   // 65536 pixels
  const int C = 256;

  // workspace layout (bf16 ushorts): xb | qkv | xo | Wqkv_b | Wproj_b  (~161 MB)
  unsigned short* xb     = (unsigned short*)d_ws;
  unsigned short* qkvb   = xb + (size_t)M * C;
  unsigned short* xob    = qkvb + (size_t)M * 3 * C;
  unsigned short* wqkvb  = xob + (size_t)M * C;
  unsigned short* wprojb = wqkvb + (size_t)3 * C * C;

  cvt_f32_to_bf16<<<(M * C / 8 + 255) / 256, 256, 0, stream>>>(x, xb, M * C);
  cvt_f32_to_bf16<<<(3 * C * C / 8 + 255) / 256, 256, 0, stream>>>(Wqkv, wqkvb, 3 * C * C);
  cvt_f32_to_bf16<<<(C * C / 8 + 255) / 256, 256, 0, stream>>>(Wproj, wprojb, C * C);

  gemm_bt<0><<<(M / 128) * (3 * C / 128), 256, 0, stream>>>(
      xb, wqkvb, (void*)qkvb, nullptr, 3 * C, 3 * C / 128);

  attn_kernel<<<(M * 16) / 256, 256, 0, stream>>>(qkvb, xob);

  gemm_bt<1><<<(M / 128) * (C / 128), 256, 0, stream>>>(
      xob, wprojb, d_out, bproj, C, C / 128);
}

// Round 7
// 129.963 us; speedup vs baseline: 2.4125x; 2.4125x over previous
//
#include <hip/hip_runtime.h>
#include <stdint.h>

// ---------------------------------------------------------------------------
// MultiDilatelocalAttention (B=4, H=W=128, C=256, heads=8, K=3, dil={2,3})
//   1) qkv = x @ Wqkv^T            (bf16 MFMA GEMM, M=65536 N=768 K=256)
//   2) dilated 3x3 local attention per (pixel, combo) thread  (R5 version)
//   3) out = xo @ Wproj^T + bproj  (bf16 MFMA GEMM, fp32 out)
// GEMM R7: BK=32 (was 64). K-loop LDS 32 KB, block LDS 34.8 KB -> 4 resident
// blocks/CU (was 2 at 64 KB) to hide per-block cold-start + barrier drains.
// Counted-vmcnt depth-2 pipeline kept (WAITVM(4), 8 K-tiles unrolled).
// T2 swizzle re-derived for 64 B rows: key=(row>>1)&3; staging fetches global
// granule (l&3)^((l>>3)&3); reads use (lane>>4)^((lane>>1)&3). (rule #21)
// attn R7: reverted to R5-measured version (R6's batched-array variant hit
// the rule-#20 scratch pattern: 5x stall, VALUBusy 34->9%, same traffic).
// ---------------------------------------------------------------------------

typedef __attribute__((ext_vector_type(8))) short bf16x8;
typedef __attribute__((ext_vector_type(4))) float f32x4;

__device__ __forceinline__ void unpack2(unsigned u, float& lo, float& hi) {
  union { unsigned u; float f; } a, b;
  a.u = u << 16;
  b.u = u & 0xffff0000u;
  lo = a.f; hi = b.f;
}
__device__ __forceinline__ unsigned short f2bf(float f) {
  union { float f; unsigned u; } x; x.f = f;
  unsigned r = x.u + 0x7fffu + ((x.u >> 16) & 1u);   // RNE
  return (unsigned short)(r >> 16);
}
__device__ __forceinline__ unsigned pk2bf(float a, float b) {
  return (unsigned)f2bf(a) | ((unsigned)f2bf(b) << 16);
}

// ------------------------------- fp32 -> bf16 ------------------------------
__global__ __launch_bounds__(256) void cvt_f32_to_bf16(
    const float* __restrict__ src, unsigned short* __restrict__ dst, int n) {
  int i = (blockIdx.x * 256 + threadIdx.x) * 8;
  if (i + 8 <= n) {
    const float4* s = (const float4*)(src + i);
    float4 a = s[0], b = s[1];
    uint4 o;
    o.x = pk2bf(a.x, a.y); o.y = pk2bf(a.z, a.w);
    o.z = pk2bf(b.x, b.y); o.w = pk2bf(b.z, b.w);
    *(uint4*)(dst + i) = o;
  } else {
    for (; i < n; ++i) dst[i] = f2bf(src[i]);
  }
}

// ------------------------- GEMM: C = A @ B^T (bf16) ------------------------
#define BARX()                                                \
  do {                                                        \
    asm volatile("s_waitcnt lgkmcnt(0)" ::: "memory");        \
    __builtin_amdgcn_s_barrier();                             \
    __builtin_amdgcn_sched_barrier(0);                        \
  } while (0)
#define WAITVM(n)                                             \
  do {                                                        \
    asm volatile("s_waitcnt vmcnt(" #n ")" ::: "memory");     \
    __builtin_amdgcn_sched_barrier(0);                        \
  } while (0)

template <int OUTF32>
__global__ __launch_bounds__(256) void gemm_bt(
    const unsigned short* __restrict__ A, const unsigned short* __restrict__ B,
    void* __restrict__ Cout, const float* __restrict__ bias,
    int N, int NT) {
  // K-loop: A0[0,4096) B0[4096,8192) A1[8192,12288) B1[12288,16384) ushorts,
  // each tile 128x32 bf16 = 8 KB. Epilogue reuses [0,17408) = 34816 B total.
  __shared__ __align__(16) unsigned short lds[17408];

  const int tid  = threadIdx.x;
  const int lane = tid & 63;
  const int wv   = tid >> 6;
  const int wr   = wv >> 1;   // wave row (0..1)
  const int wc   = wv & 1;    // wave col (0..1)

  // XCD-chunked bijective swizzle (gridDim.x % 8 == 0), N-major tile order.
  const int nwg = gridDim.x;
  const int q8  = nwg >> 3;
  const int nid = (blockIdx.x & 7) * q8 + (blockIdx.x >> 3);
  const int n0  = (nid % NT) * 128;
  const int m0  = (nid / NT) * 128;

  // staging (BK=32): per issue `it` (0..1), wave wv writes 1 KB linearly at
  // elem = it*2048 + wv*512 + l*8 -> row = it*64 + wv*16 + (l>>2), gran = l&3.
  // T2: lane fetches global granule (l&3)^key, key=(row>>1)&3=(l>>3)&3.
  const int stg_row = wv * 16 + (lane >> 2);
  const int stg_k   = ((lane & 3) ^ ((lane >> 3) & 3)) * 8;
  const unsigned short* Ag = A + (size_t)(m0 + stg_row) * 256 + stg_k;
  const unsigned short* Bg = B + (size_t)(n0 + stg_row) * 256 + stg_k;

  f32x4 acc[4][4];
#pragma unroll
  for (int i = 0; i < 4; ++i)
#pragma unroll
    for (int j = 0; j < 4; ++j) acc[i][j] = (f32x4){0.f, 0.f, 0.f, 0.f};

  const int a_r = lane & 15;   // row within 16x16 fragment (row&15)

#define STAGE(buf, kt)                                                         \
  do {                                                                         \
    const unsigned short* Asrc = Ag + (kt) * 32;                               \
    const unsigned short* Bsrc = Bg + (kt) * 32;                               \
    _Pragma("unroll")                                                          \
    for (int it = 0; it < 2; ++it) {                                           \
      __builtin_amdgcn_global_load_lds(                                        \
          (const __attribute__((address_space(1))) void*)(Asrc + (size_t)it * 64 * 256), \
          (__attribute__((address_space(3))) void*)&lds[(buf) * 8192 + it * 2048 + wv * 512], \
          16, 0, 0);                                                           \
      __builtin_amdgcn_global_load_lds(                                        \
          (const __attribute__((address_space(1))) void*)(Bsrc + (size_t)it * 64 * 256), \
          (__attribute__((address_space(3))) void*)&lds[(buf) * 8192 + 4096 + it * 2048 + wv * 512], \
          16, 0, 0);                                                           \
    }                                                                          \
  } while (0)

// read swizzle: nominal gran = lane>>4, key = (row>>1)&3 = (lane>>1)&3
// (all fragment row bases are multiples of 16, row = base + (lane&15)).
#define COMPUTE(buf)                                                           \
  do {                                                                         \
    const int gsw = (((lane >> 4) ^ ((lane >> 1) & 3))) * 8;                   \
    bf16x8 af[4], bfr[4];                                                      \
    _Pragma("unroll")                                                          \
    for (int mi = 0; mi < 4; ++mi)                                             \
      af[mi] = *(const bf16x8*)&lds[(buf) * 8192 + (wr * 64 + mi * 16 + a_r) * 32 + gsw]; \
    _Pragma("unroll")                                                          \
    for (int ni = 0; ni < 4; ++ni)                                             \
      bfr[ni] = *(const bf16x8*)&lds[(buf) * 8192 + 4096 + (wc * 64 + ni * 16 + a_r) * 32 + gsw]; \
    _Pragma("unroll")                                                          \
    for (int mi = 0; mi < 4; ++mi)                                             \
      _Pragma("unroll")                                                        \
      for (int ni = 0; ni < 4; ++ni)                                           \
        acc[mi][ni] = __builtin_amdgcn_mfma_f32_16x16x32_bf16(                 \
            af[mi], bfr[ni], acc[mi][ni], 0, 0, 0);                            \
  } while (0)

  // Depth-2 prefetch, 4 loads/wave per STAGE; counted vmcnt, never 0 until
  // the final tile. 8 K-tiles rotate buffers 0,1,0,1,...
  STAGE(0, 0);
  STAGE(1, 1);
  WAITVM(4);  BARX();
  COMPUTE(0);  BARX();
  STAGE(0, 2); WAITVM(4); BARX();
  COMPUTE(1);  BARX();
  STAGE(1, 3); WAITVM(4); BARX();
  COMPUTE(0);  BARX();
  STAGE(0, 4); WAITVM(4); BARX();
  COMPUTE(1);  BARX();
  STAGE(1, 5); WAITVM(4); BARX();
  COMPUTE(0);  BARX();
  STAGE(0, 6); WAITVM(4); BARX();
  COMPUTE(1);  BARX();
  STAGE(1, 7); WAITVM(4); BARX();
  COMPUTE(0);  BARX();
  WAITVM(0);   BARX();
  COMPUTE(1);  BARX();   // LDS about to be reused by epilogue

  // ------------------- LDS-staged coalesced epilogue -------------------
  const int cl = wc * 64 + a_r;              // local col base
  const int rl = wr * 64 + (lane >> 4) * 4;  // local row base
  if (!OUTF32) {
    // 128 rows x (128+8) bf16 = 17408 ushorts (16B-aligned rows, bank spread)
    unsigned short* eb = &lds[0];
#pragma unroll
    for (int ni = 0; ni < 4; ++ni)
#pragma unroll
      for (int mi = 0; mi < 4; ++mi)
#pragma unroll
        for (int r = 0; r < 4; ++r)
          eb[(rl + mi * 16 + r) * 136 + cl + ni * 16] = f2bf(acc[mi][ni][r]);
    BARX();   // lgkmcnt(0) drain inside: publishes ds_writes to all waves
    unsigned short* C = (unsigned short*)Cout;
#pragma unroll
    for (int p = 0; p < 8; ++p) {
      const int idx = p * 256 + tid;
      const int row = idx >> 4;
      const int seg = idx & 15;
      uint4 v = *(const uint4*)&eb[row * 136 + seg * 8];
      *(uint4*)&C[(size_t)(m0 + row) * N + n0 + seg * 8] = v;
    }
  } else {
    // f32: two 64-row halves of (128+4)-f32-stride rows (33792 B each)
    float* ef = (float*)&lds[0];
    float* C = (float*)Cout;
    float bv[4];
#pragma unroll
    for (int ni = 0; ni < 4; ++ni) bv[ni] = bias[n0 + wc * 64 + ni * 16 + a_r];
#pragma unroll
    for (int half = 0; half < 2; ++half) {
      if (wr == half) {
        const int rb = (lane >> 4) * 4;   // local row within the half
#pragma unroll
        for (int ni = 0; ni < 4; ++ni)
#pragma unroll
          for (int mi = 0; mi < 4; ++mi)
#pragma unroll
            for (int r = 0; r < 4; ++r)
              ef[(rb + mi * 16 + r) * 132 + wc * 64 + ni * 16 + a_r] =
                  acc[mi][ni][r] + bv[ni];
      }
      BARX();   // lgkmcnt(0) drain inside
#pragma unroll
      for (int p = 0; p < 8; ++p) {
        const int idx = p * 256 + tid;
        const int row = idx >> 5;
        const int seg = idx & 31;
        f32x4 v = *(const f32x4*)&ef[row * 132 + seg * 4];
        *(f32x4*)&C[(size_t)(m0 + half * 64 + row) * N + n0 + seg * 4] = v;
      }
      BARX();
    }
  }
#undef STAGE
#undef COMPUTE
}

// --------------------------- dilated local attention -----------------------
// R5-measured version (49.6 us). qkv: [pixel][768] bf16, one thread per
// (pixel, combo=branch*4+head), 32 ch; 9 zero-padded 3x3 window taps.
__global__ __launch_bounds__(256) void attn_kernel(
    const unsigned short* __restrict__ qkv, unsigned short* __restrict__ xo) {
  const int nwg = gridDim.x;
  const int q8  = nwg >> 3;
  const int bid = (blockIdx.x & 7) * q8 + (blockIdx.x >> 3);
  const int gid   = bid * 256 + threadIdx.x;
  const int combo = gid & 7;
  const int pixel = gid >> 3;
  const int w = pixel & 127;
  const int h = (pixel >> 7) & 127;
  const int b = pixel >> 14;
  const int dil = (combo >> 2) ? 3 : 2;     // DILATIONS = (2, 3)
  const int choff = combo * 32;             // = branch*128 + head*32

  const unsigned short* qp = qkv + (size_t)pixel * 768 + choff;
  float q[32];
#pragma unroll
  for (int t = 0; t < 4; ++t) {
    uint4 u = *(const uint4*)(qp + t * 8);
    unpack2(u.x, q[t * 8 + 0], q[t * 8 + 1]);
    unpack2(u.y, q[t * 8 + 2], q[t * 8 + 3]);
    unpack2(u.z, q[t * 8 + 4], q[t * 8 + 5]);
    unpack2(u.w, q[t * 8 + 6], q[t * 8 + 7]);
  }

  // scores: zero-padded unfold => OOB taps have score exactly 0 (not -inf)
  float sc[9];
#pragma unroll
  for (int i = 0; i < 3; ++i) {
#pragma unroll
    for (int j = 0; j < 3; ++j) {
      const int hh = h + (i - 1) * dil;
      const int ww = w + (j - 1) * dil;
      float s = 0.f;
      if ((unsigned)hh < 128u && (unsigned)ww < 128u) {
        const unsigned short* kp =
            qkv + (size_t)((((b << 7) | hh) << 7) | ww) * 768 + 256 + choff;
#pragma unroll
        for (int t = 0; t < 4; ++t) {
          uint4 u = *(const uint4*)(kp + t * 8);
          float a0, a1;
          unpack2(u.x, a0, a1); s += q[t * 8 + 0] * a0 + q[t * 8 + 1] * a1;
          unpack2(u.y, a0, a1); s += q[t * 8 + 2] * a0 + q[t * 8 + 3] * a1;
          unpack2(u.z, a0, a1); s += q[t * 8 + 4] * a0 + q[t * 8 + 5] * a1;
          unpack2(u.w, a0, a1); s += q[t * 8 + 6] * a0 + q[t * 8 + 7] * a1;
        }
      }
      sc[i * 3 + j] = s * 0.17677669529663687f;   // 32^-0.5
    }
  }

  float mx = sc[0];
#pragma unroll
  for (int t = 1; t < 9; ++t) mx = fmaxf(mx, sc[t]);
  float wgt[9], sum = 0.f;
#pragma unroll
  for (int t = 0; t < 9; ++t) { wgt[t] = __expf(sc[t] - mx); sum += wgt[t]; }
  const float inv = 1.f / sum;

  float o[32];
#pragma unroll
  for (int t = 0; t < 32; ++t) o[t] = 0.f;
#pragma unroll
  for (int i = 0; i < 3; ++i) {
#pragma unroll
    for (int j = 0; j < 3; ++j) {
      const int hh = h + (i - 1) * dil;
      const int ww = w + (j - 1) * dil;
      if ((unsigned)hh < 128u && (unsigned)ww < 128u) {
        const float wv = wgt[i * 3 + j] * inv;
        const unsigned short* vp =
            qkv + (size_t)((((b << 7) | hh) << 7) | ww) * 768 + 512 + choff;
#pragma unroll
        for (int t = 0; t < 4; ++t) {
          uint4 u = *(const uint4*)(vp + t * 8);
          float a0, a1;
          unpack2(u.x, a0, a1); o[t * 8 + 0] += wv * a0; o[t * 8 + 1] += wv * a1;
          unpack2(u.y, a0, a1); o[t * 8 + 2] += wv * a0; o[t * 8 + 3] += wv * a1;
          unpack2(u.z, a0, a1); o[t * 8 + 4] += wv * a0; o[t * 8 + 5] += wv * a1;
          unpack2(u.w, a0, a1); o[t * 8 + 6] += wv * a0; o[t * 8 + 7] += wv * a1;
        }
      }
    }
  }

  unsigned short* op = xo + (size_t)pixel * 256 + choff;
#pragma unroll
  for (int t = 0; t < 4; ++t) {
    uint4 u;
    u.x = pk2bf(o[t * 8 + 0], o[t * 8 + 1]);
    u.y = pk2bf(o[t * 8 + 2], o[t * 8 + 3]);
    u.z = pk2bf(o[t * 8 + 4], o[t * 8 + 5]);
    u.w = pk2bf(o[t * 8 + 6], o[t * 8 + 7]);
    *(uint4*)(op + t * 8) = u;
  }
}

// ---------------------------------------------------------------------------
extern "C" void kernel_launch(void* const* d_in, const int* in_sizes, int n_in,
                              void* d_out, int out_size, void* d_ws, size_t ws_size,
                              hipStream_t stream) {
  const float* x     = (const float*)d_in[0];
  const float* Wqkv  = (const float*)d_in[1];
  const float* Wproj = (const float*)d_in[2];
  const float* bproj = (const float*)d_in[3];

  const int M = 4 * 128 * 128;   // 65536 pixels
  const int C = 256;

  // workspace layout (bf16 ushorts): xb | qkv | xo | Wqkv_b | Wproj_b  (~161 MB)
  unsigned short* xb     = (unsigned short*)d_ws;
  unsigned short* qkvb   = xb + (size_t)M * C;
  unsigned short* xob    = qkvb + (size_t)M * 3 * C;
  unsigned short* wqkvb  = xob + (size_t)M * C;
  unsigned short* wprojb = wqkvb + (size_t)3 * C * C;

  cvt_f32_to_bf16<<<(M * C / 8 + 255) / 256, 256, 0, stream>>>(x, xb, M * C);
  cvt_f32_to_bf16<<<(3 * C * C / 8 + 255) / 256, 256, 0, stream>>>(Wqkv, wqkvb, 3 * C * C);
  cvt_f32_to_bf16<<<(C * C / 8 + 255) / 256, 256, 0, stream>>>(Wproj, wprojb, C * C);

  gemm_bt<0><<<(M / 128) * (3 * C / 128), 256, 0, stream>>>(
      xb, wqkvb, (void*)qkvb, nullptr, 3 * C, 3 * C / 128);

  attn_kernel<<<(M * 8) / 256, 256, 0, stream>>>(qkvb, xob);

  gemm_bt<1><<<(M / 128) * (C / 128), 256, 0, stream>>>(
      xob, wprojb, d_out, bproj, C, C / 128);
}